// Round 3
// baseline (16276.784 us; speedup 1.0000x reference)
//
#include <hip/hip_runtime.h>
#include <hip/hip_bf16.h>

#define SEQ   512
#define BATCH 256
#define DIN   512
#define DLAT  1024

#define NBG          16                    // batch groups of 16 rows
#define WAVES_PER_BG 32                    // 32 cols per wave
#define SCAN_BLOCKS  (NBG * WAVES_PER_BG)  // 512 one-wave blocks
#define NFLAGS       (NBG * WAVES_PER_BG)

typedef __attribute__((ext_vector_type(8))) short bf16x8;
typedef __attribute__((ext_vector_type(4))) float f32x4;
typedef unsigned long long u64;

__device__ __forceinline__ unsigned short f2bf(float f) {
    union { float f; unsigned u; } v; v.f = f;
    unsigned r = v.u + 0x7FFFu + ((v.u >> 16) & 1u);   // RNE
    return (unsigned short)(r >> 16);
}

__global__ void convert_weights(const float* __restrict__ Wi, const float* __restrict__ Wh,
                                unsigned short* __restrict__ Wib, unsigned short* __restrict__ Whb,
                                unsigned int* __restrict__ flags) {
    const int nWi = DLAT * DIN;
    const int nWh = DLAT * DLAT;
    const int t0 = blockIdx.x * blockDim.x + threadIdx.x;
    if (t0 < NFLAGS) flags[t0] = 0;
    for (int idx = t0; idx < nWi + nWh; idx += gridDim.x * blockDim.x) {
        if (idx < nWi) Wib[idx] = f2bf(Wi[idx]);
        else           Whb[idx - nWi] = f2bf(Wh[idx - nWi]);
    }
}

// Phase 1: xi = x @ Wi^T. M=SEQ*BATCH, K=DIN, N=DLAT. (validated rounds 1-2)
__global__ __launch_bounds__(1024) void xproj_kernel(const float* __restrict__ x,
                                                     const unsigned short* __restrict__ Wib,
                                                     float* __restrict__ xi) {
    const int tid  = threadIdx.x;
    const int lane = tid & 63;
    const int w    = tid >> 6;
    const int l15  = lane & 15;
    const int l4   = lane >> 4;
    const int mblk = blockIdx.x >> 2;
    const int nblk = blockIdx.x & 3;
    const size_t m0 = (size_t)mblk * 64 + (w & 3) * 16;
    const int    n0 = nblk * 256 + (w >> 2) * 64;

    const float* xp = x + (m0 + l15) * DIN + l4 * 8;

    f32x4 acc[4];
    #pragma unroll
    for (int j = 0; j < 4; ++j) acc[j] = (f32x4)0.f;

    const unsigned short* bp[4];
    #pragma unroll
    for (int j = 0; j < 4; ++j)
        bp[j] = Wib + (size_t)(n0 + j * 16 + l15) * DIN + l4 * 8;

    #pragma unroll 4
    for (int kc = 0; kc < DIN / 32; ++kc) {
        f32x4 a0 = *(const f32x4*)(xp + kc * 32);
        f32x4 a1 = *(const f32x4*)(xp + kc * 32 + 4);
        bf16x8 af;
        #pragma unroll
        for (int i = 0; i < 4; ++i) { af[i] = (short)f2bf(a0[i]); af[i + 4] = (short)f2bf(a1[i]); }
        #pragma unroll
        for (int j = 0; j < 4; ++j) {
            bf16x8 bf = *(const bf16x8*)(bp[j] + kc * 32);
            acc[j] = __builtin_amdgcn_mfma_f32_16x16x32_bf16(af, bf, acc[j], 0, 0, 0);
        }
    }
    #pragma unroll
    for (int j = 0; j < 4; ++j) {
        const int col = n0 + j * 16 + l15;
        #pragma unroll
        for (int i = 0; i < 4; ++i)
            xi[(m0 + l4 * 4 + i) * DLAT + col] = acc[j][i];
    }
}

// Phase 2: 512 one-wave blocks = 16 bg x 32 waves. Wave owns 32 output cols;
// W_h slice (32x1024 bf16 = 256 VGPR) resident in registers. h exchanged via
// agent-coherent (L2-bypassing) loads/stores of double-buffered bf16 hbuf in
// L3. bg-local monotone flag barrier (release store / acquire spin), one per
// step. No LDS, no __syncthreads, no grid.sync.
__global__ __launch_bounds__(64, 1) void rnn_scan(
        const unsigned short* __restrict__ Whb,
        const float* __restrict__ bh,
        float* __restrict__ hs,                 // xi on entry; overwritten with h
        float* __restrict__ hfin,
        unsigned short* __restrict__ hbuf,      // [2][BATCH][DLAT] bf16
        unsigned int* __restrict__ flags) {     // [NBG][32] monotone counters
    const int lane = threadIdx.x;
    const int l15  = lane & 15;
    const int l4   = lane >> 4;                 // 0..3
    const int bg   = blockIdx.x >> 5;           // 0..15
    const int wv   = blockIdx.x & 31;           // 0..31
    const int b0   = bg * 16;
    const int col0 = wv * 32 + l15;
    const int col1 = wv * 32 + 16 + l15;

    // ---- W_h fragments resident in VGPRs (2 n-tiles x 32 kk = 256 VGPRs) ----
    bf16x8 wf0[32], wf1[32];
    {
        const unsigned short* wp0 = Whb + (size_t)col0 * DLAT + l4 * 8;
        const unsigned short* wp1 = Whb + (size_t)col1 * DLAT + l4 * 8;
        #pragma unroll
        for (int kk = 0; kk < 32; ++kk) {
            wf0[kk] = *(const bf16x8*)(wp0 + kk * 32);
            wf1[kk] = *(const bf16x8*)(wp1 + kk * 32);
        }
    }
    const float bias0 = bh[col0];
    const float bias1 = bh[col1];

    unsigned int* myflag  = flags + bg * 32 + wv;
    const u64*    flag64  = (const u64*)(flags + bg * 32);   // 16 u64 = 32 flags
    const int     fidx    = lane & 15;

    const int myrow = b0 + l4 * 4;   // first of this lane's 4 output rows

    // xi for t=0
    float xc0[4], xc1[4];
    #pragma unroll
    for (int i = 0; i < 4; ++i) {
        xc0[i] = hs[(size_t)(myrow + i) * DLAT + col0];
        xc1[i] = hs[(size_t)(myrow + i) * DLAT + col1];
    }

    for (int t = 0; t < SEQ; ++t) {
        // ---- prefetch xi for t+1 (HBM latency hides under spin + K-loop) ----
        float nx0[4], nx1[4];
        if (t + 1 < SEQ) {
            const float* xp = hs + (size_t)(t + 1) * BATCH * DLAT;
            #pragma unroll
            for (int i = 0; i < 4; ++i) {
                nx0[i] = xp[(size_t)(myrow + i) * DLAT + col0];
                nx1[i] = xp[(size_t)(myrow + i) * DLAT + col1];
            }
        }

        f32x4 acc0 = (f32x4)0.f, acc1 = (f32x4)0.f;

        if (t > 0) {
            // ---- bg-local barrier: wait until all 32 same-bg waves set flag>=t
            const unsigned tgt = (unsigned)t;
            for (;;) {
                u64 f = __hip_atomic_load(flag64 + fidx, __ATOMIC_ACQUIRE,
                                          __HIP_MEMORY_SCOPE_AGENT);
                int ok = ((unsigned)f >= tgt) && ((unsigned)(f >> 32) >= tgt);
                if (__all(ok)) break;
            }

            // ---- K-loop: A-frags direct from hbuf (L3), two halves of 16 kk
            const u64* ap = (const u64*)hbuf
                          + ((size_t)((t + 1) & 1) * BATCH + b0 + l15) * (DLAT / 4)
                          + l4 * 2;
            u64 q[32];
            #pragma unroll
            for (int kk = 0; kk < 16; ++kk) {
                q[kk * 2]     = __hip_atomic_load(ap + kk * 8,     __ATOMIC_RELAXED, __HIP_MEMORY_SCOPE_AGENT);
                q[kk * 2 + 1] = __hip_atomic_load(ap + kk * 8 + 1, __ATOMIC_RELAXED, __HIP_MEMORY_SCOPE_AGENT);
            }
            #pragma unroll
            for (int kk = 0; kk < 16; ++kk) {
                union { u64 qq[2]; bf16x8 v; } u;
                u.qq[0] = q[kk * 2]; u.qq[1] = q[kk * 2 + 1];
                acc0 = __builtin_amdgcn_mfma_f32_16x16x32_bf16(u.v, wf0[kk], acc0, 0, 0, 0);
                acc1 = __builtin_amdgcn_mfma_f32_16x16x32_bf16(u.v, wf1[kk], acc1, 0, 0, 0);
            }
            #pragma unroll
            for (int kk = 0; kk < 16; ++kk) {
                q[kk * 2]     = __hip_atomic_load(ap + (kk + 16) * 8,     __ATOMIC_RELAXED, __HIP_MEMORY_SCOPE_AGENT);
                q[kk * 2 + 1] = __hip_atomic_load(ap + (kk + 16) * 8 + 1, __ATOMIC_RELAXED, __HIP_MEMORY_SCOPE_AGENT);
            }
            #pragma unroll
            for (int kk = 0; kk < 16; ++kk) {
                union { u64 qq[2]; bf16x8 v; } u;
                u.qq[0] = q[kk * 2]; u.qq[1] = q[kk * 2 + 1];
                acc0 = __builtin_amdgcn_mfma_f32_16x16x32_bf16(u.v, wf0[kk + 16], acc0, 0, 0, 0);
                acc1 = __builtin_amdgcn_mfma_f32_16x16x32_bf16(u.v, wf1[kk + 16], acc1, 0, 0, 0);
            }
        }

        // ---- epilogue: tanh, write hs (f32, HBM) + hbuf (bf16, coherent) ----
        float* hsw = hs + (size_t)t * BATCH * DLAT;
        unsigned short* hbw = hbuf + (size_t)(t & 1) * BATCH * DLAT;
        #pragma unroll
        for (int i = 0; i < 4; ++i) {
            const size_t row = (size_t)(myrow + i);
            float v0 = acc0[i] + xc0[i] + bias0;
            float v1 = acc1[i] + xc1[i] + bias1;
            v0 = fminf(fmaxf(v0, -15.f), 15.f);
            v1 = fminf(fmaxf(v1, -15.f), 15.f);
            float e0 = __expf(2.f * v0);
            float e1 = __expf(2.f * v1);
            float h0 = 1.f - 2.f * __builtin_amdgcn_rcpf(e0 + 1.f);
            float h1 = 1.f - 2.f * __builtin_amdgcn_rcpf(e1 + 1.f);
            hsw[row * DLAT + col0] = h0;
            hsw[row * DLAT + col1] = h1;
            __hip_atomic_store(hbw + row * DLAT + col0, f2bf(h0), __ATOMIC_RELAXED, __HIP_MEMORY_SCOPE_AGENT);
            __hip_atomic_store(hbw + row * DLAT + col1, f2bf(h1), __ATOMIC_RELAXED, __HIP_MEMORY_SCOPE_AGENT);
            if (t == SEQ - 1) {
                hfin[row * DLAT + col0] = h0;
                hfin[row * DLAT + col1] = h1;
            }
        }

        // ---- release: h[t] done (orders all prior wave memory ops) ----
        if (lane == 0)
            __hip_atomic_store(myflag, (unsigned)(t + 1), __ATOMIC_RELEASE,
                               __HIP_MEMORY_SCOPE_AGENT);

        #pragma unroll
        for (int i = 0; i < 4; ++i) { xc0[i] = nx0[i]; xc1[i] = nx1[i]; }
    }
}

extern "C" void kernel_launch(void* const* d_in, const int* in_sizes, int n_in,
                              void* d_out, int out_size, void* d_ws, size_t ws_size,
                              hipStream_t stream) {
    const float* x  = (const float*)d_in[0];
    const float* Wi = (const float*)d_in[1];
    const float* Wh = (const float*)d_in[2];
    const float* bh = (const float*)d_in[3];

    float* out  = (float*)d_out;
    float* hfin = out;                                  // [BATCH, DLAT]
    float* hs   = out + (size_t)BATCH * DLAT;           // [SEQ, BATCH, DLAT], xi then h

    unsigned int*   flags = (unsigned int*)d_ws;                          // 2 KB
    unsigned short* Wib   = (unsigned short*)((char*)d_ws + 4096);        // 1 MB
    unsigned short* Whb   = Wib + (size_t)DLAT * DIN;                     // 2 MB
    unsigned short* hbuf  = Whb + (size_t)DLAT * DLAT;                    // 1 MB

    convert_weights<<<512, 256, 0, stream>>>(Wi, Wh, Wib, Whb, flags);

    const int M = SEQ * BATCH;
    xproj_kernel<<<(M / 64) * (DLAT / 256), 1024, 0, stream>>>(x, Wib, hs);

    rnn_scan<<<SCAN_BLOCKS, 64, 0, stream>>>(Whb, bh, hs, hfin, hbuf, flags);
}